// Round 1
// baseline (8875.754 us; speedup 1.0000x reference)
//
#include <hip/hip_runtime.h>
#include <hip/hip_fp16.h>
#include <cstddef>

#define T_LEN 4096
#define HID 150
#define G4 600
#define NC 300

typedef __attribute__((ext_vector_type(8))) short bf16x8;      // 8 bf16 = 4 VGPRs
typedef __attribute__((ext_vector_type(8))) _Float16 f16x8;    // 8 fp16 = 4 VGPRs
typedef __attribute__((ext_vector_type(4))) float f32x4;

// raw barrier: waits LDS ops only, leaves global loads/stores in flight
__device__ __forceinline__ void barrier_lgkm() {
  asm volatile("s_waitcnt lgkmcnt(0)\n\ts_barrier" ::: "memory");
}

__device__ __forceinline__ float fsig(float x) {
  return __builtin_amdgcn_rcpf(1.f + __expf(-x));
}
__device__ __forceinline__ float ftanh(float x) {
  float ax = fabsf(x);
  float e = __expf(2.f * ax);
  float t = 1.f - 2.f * __builtin_amdgcn_rcpf(e + 1.f);
  return copysignf(t, x);
}
__device__ __forceinline__ unsigned short f2bf(float f) {  // RNE fp32->bf16
  unsigned u = __builtin_bit_cast(unsigned, f);
  u += 0x7fff + ((u >> 16) & 1);
  return (unsigned short)(u >> 16);
}

// ---------------- LSTM scan via MFMA: gate-local redesign (r9) -----------------
// Replaces the r3 two-phase structure (g_s LDS roundtrip + 2 barriers/step,
// 1743-1815 cyc/step). New: A = Whh with GATE-INTERLEAVED rows (tile rows =
// i,f,g,o of unit0, i,f,g,o of unit1, ...), B = h broadcast into all 16 cols
// (one conflict-free ds_read_b128 per kk). With C/D layout row=4*lq+reg,
// col=lrow, each lane's acc[j][0..3] holds the 4 gate pre-activations of unit
// 4*tile+lq. Lane lrow==j selects acc[j] (unrolled cndmask) and runs the gate
// chain in-register -> no g_s buffer, ONE barrier/step (h double-buffered).
// Same MFMA count and numerics as r3 (A/B roles swapped only).
__global__ __launch_bounds__(512, 2) void lstm_scan(
    const float* __restrict__ whh_solv, const float* __restrict__ whh_solu,
    const float* __restrict__ xg_base,
    float* __restrict__ o32v, float* __restrict__ o32u,
    __half* __restrict__ o16v, __half* __restrict__ o16u, int layer, int w32)
{
  __shared__ __align__(16) unsigned short hbuf[2][160];  // bf16 h, double-buffered
  const int c = blockIdx.x;
  const int net = c >> 1, dir = c & 1;
  const float* Whh = (net ? whh_solu : whh_solv) + (size_t)(layer * 2 + dir) * (G4 * HID);
  const float* xg = xg_base + (size_t)c * T_LEN * G4;
  float* out32 = (net ? o32u : o32v) + dir * HID;     // row stride NC (if w32)
  __half* out16 = (net ? o16u : o16v) + dir * HID;    // row stride 320
  const int tid = threadIdx.x;
  const int lane = tid & 63, wv = tid >> 6;
  const int lrow = lane & 15, lq = lane >> 4;

  // A-fragments: tile T = wv+8j covers units 4T..4T+3.
  // A[row=lrow][k] = Whh[(lrow&3)*HID + (4T + (lrow>>2))][k]; zero-padded.
  bf16x8 wfr[5][5];  // [j][kk]
#pragma unroll
  for (int j = 0; j < 5; j++) {
    const int T = wv + 8 * j;
    const int un = 4 * T + (lrow >> 2);   // hidden-unit index (0..159)
    const int gt = lrow & 3;              // gate 0..3 = i,f,g,o
#pragma unroll
    for (int kk = 0; kk < 5; kk++) {
      bf16x8 b;
#pragma unroll
      for (int i = 0; i < 8; i++) {
        const int k = kk * 32 + lq * 8 + i;
        const float v = (un < HID && k < HID) ? Whh[(size_t)(gt * HID + un) * HID + k] : 0.f;
        b[i] = (short)f2bf(v);
      }
      wfr[j][kk] = b;
    }
  }
  if (tid < 160) hbuf[0][tid] = 0;

  // gate-lane state: lanes with lrow<5 own unit u (one unit per lane; 160 slots)
  const int u = 4 * (wv + 8 * lrow) + lq;
  float cst = 0.f;
  float xr0 = 0.f, xr1 = 0.f, xr2 = 0.f, xr3 = 0.f;
  if (lrow < 5 && u < HID) {
    const int t0 = dir ? (T_LEN - 1) : 0;
    const float* xgr = xg + (size_t)t0 * G4 + u;
    xr0 = xgr[0]; xr1 = xgr[HID]; xr2 = xgr[2 * HID]; xr3 = xgr[3 * HID];
  }
  barrier_lgkm();

  for (int s = 0; s < T_LEN; s++) {
    const int t = dir ? (T_LEN - 1 - s) : s;
    const unsigned short* hc = hbuf[s & 1];
    unsigned short* hn = hbuf[(s & 1) ^ 1];
    // B-frags: B[k][col] = h[k] for every col -> addr depends only on lq
    // (16-way same-address broadcast per group: conflict-free).
    bf16x8 hb[5];
#pragma unroll
    for (int kk = 0; kk < 5; kk++)
      hb[kk] = *(const bf16x8*)&hc[kk * 32 + lq * 8];
    f32x4 acc[5];
#pragma unroll
    for (int j = 0; j < 5; j++) acc[j] = (f32x4){0.f, 0.f, 0.f, 0.f};
#pragma unroll
    for (int kk = 0; kk < 5; kk++)
#pragma unroll
      for (int j = 0; j < 5; j++)
        acc[j] = __builtin_amdgcn_mfma_f32_16x16x32_bf16(wfr[j][kk], hb[kk], acc[j], 0, 0, 0);
    // lane (lrow<5, lq): acc[lrow][r] = gate r of unit u. Gates fully in-wave.
    if (lrow < 5) {
      float gi = 0.f, gf = 0.f, gg = 0.f, go = 0.f;
#pragma unroll
      for (int j = 0; j < 5; j++)
        if (lrow == j) { gi = acc[j][0]; gf = acc[j][1]; gg = acc[j][2]; go = acc[j][3]; }
      gi += xr0; gf += xr1; gg += xr2; go += xr3;
      if (s + 1 < T_LEN && u < HID) {  // prefetch next xg row (in flight past barrier)
        const int tn = dir ? (T_LEN - 2 - s) : (s + 1);
        const float* xgr = xg + (size_t)tn * G4 + u;
        xr0 = xgr[0]; xr1 = xgr[HID]; xr2 = xgr[2 * HID]; xr3 = xgr[3 * HID];
      }
      const float iv = fsig(gi), fv = fsig(gf), gv = ftanh(gg), ov = fsig(go);
      cst = fv * cst + iv * gv;
      const float hv = ov * ftanh(cst);
      unsigned short hw = 0;               // pad units (u>=150) stay zero
      if (u < HID) {
        hw = f2bf(hv);                     // matvec input rounded; c/h state fp32
        out16[(size_t)t * 320 + u] = __float2half(hv);
        if (w32) out32[(size_t)t * NC + u] = hv;
      }
      hn[u] = hw;
    }
    barrier_lgkm();   // ONE barrier/step: hn becomes hc of step s+1
  }
}

// ---------------- fp32 -> fp16 conversion helpers ------------------------------
// Wihh[8][640][320]: slot s = l*4 + net*2 + dir, zero-padded rows/cols
__global__ void conv_w(const float* __restrict__ wv, const float* __restrict__ wu,
                       __half* __restrict__ dst)
{
  const int gid = blockIdx.x * 256 + threadIdx.x;
  if (gid >= 8 * 640 * 320) return;
  const int k = gid % 320, j = (gid / 320) % 640, s = gid / (320 * 640);
  const int l = s >> 2, net = (s >> 1) & 1, dir = s & 1;
  float v = 0.f;
  if (j < G4 && k < NC) {
    const float* src = (net ? wu : wv) + (size_t)(l * 2 + dir) * (G4 * NC);
    v = src[(size_t)j * NC + k];
  }
  dst[gid] = __float2half(v);
}

// X fp32 [rows][300] -> Xh fp16 [rows][320] zero-padded
__global__ void conv_x(const float* __restrict__ src, __half* __restrict__ dst, int rows)
{
  const int gid = blockIdx.x * 256 + threadIdx.x;
  if (gid >= rows * 320) return;
  const int k = gid % 320, m = gid / 320;
  dst[gid] = __float2half(k < NC ? src[(size_t)m * NC + k] : 0.f);
}

// X fp32 [4096][300] -> XT fp16 [320][4096] (rows >= 300 zeroed)
__global__ void conv_t(const float* __restrict__ src, __half* __restrict__ dst)
{
  const int gid = blockIdx.x * 256 + threadIdx.x;
  if (gid >= 320 * 4096) return;
  const int m = gid % 4096, f = gid / 4096;
  dst[gid] = __float2half(f < NC ? src[(size_t)m * NC + f] : 0.f);
}

__global__ void zero_f(float* __restrict__ p, int n) {
  const int i = blockIdx.x * 256 + threadIdx.x;
  if (i < n) p[i] = 0.f;
}

// ---------------- xg = X @ Wih^T + b via fp16 MFMA -----------------------------
// grid (64 m-blocks, 4 chains), block 256 (4 waves, 16 rows each). N=640, K=320.
__global__ __launch_bounds__(256) void xg_mfma(
    const __half* __restrict__ Av, const __half* __restrict__ Au,
    const __half* __restrict__ W,   // Wihh + layer*4*640*320
    const float* __restrict__ bihv, const float* __restrict__ bhhv,
    const float* __restrict__ bihu, const float* __restrict__ bhhu,
    float* __restrict__ xg, int layer)
{
  const int tid = threadIdx.x;
  const int lane = tid & 63, wv = tid >> 6;
  const int ln = lane & 15, q = lane >> 4;
  const int chain = blockIdx.y;
  const __half* A = (chain >= 2) ? Au : Av;
  const __half* Wc = W + (size_t)chain * 640 * 320;
  const float* bi = ((chain >= 2) ? bihu : bihv) + (size_t)(layer * 2 + (chain & 1)) * G4;
  const float* bh = ((chain >= 2) ? bhhu : bhhv) + (size_t)(layer * 2 + (chain & 1)) * G4;
  float* C = xg + (size_t)chain * T_LEN * G4;
  const int m0 = blockIdx.x * 64 + wv * 16;
  const __half* Arow = A + (size_t)(m0 + ln) * 320;

  for (int nc = 0; nc < 4; nc++) {       // 4 chunks x 160 cols
    f32x4 acc[10];
#pragma unroll
    for (int j = 0; j < 10; j++) acc[j] = (f32x4){0.f, 0.f, 0.f, 0.f};
    for (int kk = 0; kk < 10; kk++) {
      const f16x8 afr = *(const f16x8*)(Arow + kk * 32 + q * 8);
#pragma unroll
      for (int j = 0; j < 10; j++) {
        const int n = nc * 160 + j * 16 + ln;
        const f16x8 bfr = *(const f16x8*)(Wc + (size_t)n * 320 + kk * 32 + q * 8);
        acc[j] = __builtin_amdgcn_mfma_f32_16x16x32_f16(afr, bfr, acc[j], 0, 0, 0);
      }
    }
#pragma unroll
    for (int j = 0; j < 10; j++) {
      const int n = nc * 160 + j * 16 + ln;
      if (n < G4) {
        const float bias = bi[n] + bh[n];
#pragma unroll
        for (int r = 0; r < 4; r++)
          C[(size_t)(m0 + q * 4 + r) * G4 + n] = acc[j][r] + bias;
      }
    }
  }
}

// ------- S GEMM: AH[m][n] = fp16(Hh[m] . Gh[n]), raw scores (no exp) -----------
// grid (64 m-blocks, 4 n-quadrants), block 256. Softmax shift/normalization
// happens later on the ROUNDED values (self-consistent).
__global__ __launch_bounds__(256) void s_gemm(
    const __half* __restrict__ Hh, const __half* __restrict__ Gh,
    __half* __restrict__ AH)
{
  const int tid = threadIdx.x;
  const int lane = tid & 63, wv = tid >> 6;
  const int ln = lane & 15, q = lane >> 4;
  const int m0 = blockIdx.x * 64 + wv * 16;
  const __half* Arow = Hh + (size_t)(m0 + ln) * 320;
  f16x8 afr[10];
#pragma unroll
  for (int kk = 0; kk < 10; kk++) afr[kk] = *(const f16x8*)(Arow + kk * 32 + q * 8);
  const int nt0 = blockIdx.y * 64;
  for (int nt = 0; nt < 64; nt++) {
    const int n = 16 * (nt0 + nt) + ln;
    const __half* Brow = Gh + (size_t)n * 320;
    f32x4 acc = (f32x4){0.f, 0.f, 0.f, 0.f};
#pragma unroll
    for (int kk = 0; kk < 10; kk++) {
      const f16x8 bfr = *(const f16x8*)(Brow + kk * 32 + q * 8);
      acc = __builtin_amdgcn_mfma_f32_16x16x32_f16(afr[kk], bfr, acc, 0, 0, 0);
    }
#pragma unroll
    for (int r = 0; r < 4; r++)
      AH[(size_t)(m0 + q * 4 + r) * 4096 + n] = __float2half(acc[r]);
  }
}

// ------- rowsum: il[m] = 1 / sum_n exp(S[m][n] - 30)  (one block per row) ------
__global__ __launch_bounds__(256) void rowsum_k(const __half* __restrict__ AH,
                                                float* __restrict__ il)
{
  const int m = blockIdx.x, tid = threadIdx.x;
  const __half* row = AH + (size_t)m * 4096;
  float s = 0.f;
  for (int i = tid * 8; i < 4096; i += 2048) {
    const f16x8 v = *(const f16x8*)(row + i);
#pragma unroll
    for (int j = 0; j < 8; j++) s += __expf(fminf((float)v[j] - 30.f, 80.f));
  }
#pragma unroll
  for (int off = 32; off > 0; off >>= 1) s += __shfl_down(s, off);
  __shared__ float red[4];
  if ((tid & 63) == 0) red[tid >> 6] = s;
  __syncthreads();
  if (tid == 0) il[m] = 1.f / (red[0] + red[1] + red[2] + red[3]);
}

// ------- scale: AH = fp16( exp(S-30) * il[m] ), in place -----------------------
__global__ __launch_bounds__(256) void scale_k(__half* __restrict__ AH,
                                               const float* __restrict__ il)
{
  const size_t gid = (size_t)blockIdx.x * 256 + threadIdx.x;  // f16x8 chunk id
  const int m = (int)(gid >> 9);                              // 512 chunks/row
  const float ilm = il[m];
  f16x8 v = *(f16x8*)(AH + gid * 8);
#pragma unroll
  for (int j = 0; j < 8; j++)
    v[j] = (_Float16)(__expf(fminf((float)v[j] - 30.f, 80.f)) * ilm);
  *(f16x8*)(AH + gid * 8) = v;
}

// ------- P = AH @ GhT' and Q = AH^T @ HhT' in ONE dispatch (128 blocks) --------
__global__ __launch_bounds__(256) void pq_mfma(
    const __half* __restrict__ AH, const __half* __restrict__ GhT,
    const __half* __restrict__ HhT,
    float* __restrict__ Pb, float* __restrict__ Qb)
{
  __shared__ __align__(16) _Float16 Ats[64][72];  // qt staging, pitch 144 B
  const int tid = threadIdx.x;
  const int lane = tid & 63, wv = tid >> 6;
  const int ln = lane & 15, q = lane >> 4;

  if (blockIdx.x < 64) {
    // ---- P part: M=4096 rows of AH, N=320(store 300), K=4096 ----
    const int m0 = blockIdx.x * 64 + wv * 16;
    const __half* Arow = AH + (size_t)(m0 + ln) * 4096;
    for (int nc = 0; nc < 2; nc++) {
      f32x4 acc[10];
#pragma unroll
      for (int j = 0; j < 10; j++) acc[j] = (f32x4){0.f, 0.f, 0.f, 0.f};
      for (int kk = 0; kk < 128; kk++) {
        const f16x8 afr = *(const f16x8*)(Arow + kk * 32 + q * 8);
#pragma unroll
        for (int j = 0; j < 10; j++) {
          const int n = nc * 160 + j * 16 + ln;
          const f16x8 bfr = *(const f16x8*)(GhT + (size_t)n * 4096 + kk * 32 + q * 8);
          acc[j] = __builtin_amdgcn_mfma_f32_16x16x32_f16(afr, bfr, acc[j], 0, 0, 0);
        }
      }
#pragma unroll
      for (int j = 0; j < 10; j++) {
        const int n = nc * 160 + j * 16 + ln;
        if (n < NC) {
#pragma unroll
          for (int r = 0; r < 4; r++)
            Pb[(size_t)(m0 + q * 4 + r) * NC + n] = acc[j][r];
        }
      }
    }
  } else {
    // ---- Q part: Q[j][f] = sum_i a[i][j] H[i][f]; a transposed via LDS ----
    const int j0 = (blockIdx.x - 64) * 64;
    f32x4 acc[20];
#pragma unroll
    for (int j = 0; j < 20; j++) acc[j] = (f32x4){0.f, 0.f, 0.f, 0.f};
    const int il8 = tid >> 2, j8 = (tid & 3) * 16;  // staging role
    for (int ic = 0; ic < 4096; ic += 64) {
      __syncthreads();
      {
        const __half* src = AH + (size_t)(ic + il8) * 4096 + j0 + j8;
        const f16x8 v0 = *(const f16x8*)src;
        const f16x8 v1 = *(const f16x8*)(src + 8);
#pragma unroll
        for (int jj = 0; jj < 8; jj++) Ats[j8 + jj][il8] = v0[jj];
#pragma unroll
        for (int jj = 0; jj < 8; jj++) Ats[j8 + 8 + jj][il8] = v1[jj];
      }
      __syncthreads();
#pragma unroll
      for (int s = 0; s < 2; s++) {
        const f16x8 afr = *(const f16x8*)&Ats[wv * 16 + ln][s * 32 + q * 8];
        const __half* bbase = HhT + ic + s * 32 + q * 8;
#pragma unroll
        for (int j = 0; j < 20; j++) {
          const f16x8 bfr = *(const f16x8*)(bbase + (size_t)(j * 16 + ln) * 4096);
          acc[j] = __builtin_amdgcn_mfma_f32_16x16x32_f16(afr, bfr, acc[j], 0, 0, 0);
        }
      }
    }
#pragma unroll
    for (int j = 0; j < 20; j++) {
      const int f = j * 16 + ln;
      if (f < NC) {
#pragma unroll
        for (int r = 0; r < 4; r++)
          Qb[(size_t)(j0 + wv * 16 + q * 4 + r) * NC + f] = acc[j][r];
      }
    }
  }
}

// ---------------- tail ---------------------------------------------------------
__global__ void reduce_uv(const float* __restrict__ X, const float* __restrict__ Yp,
                          float* __restrict__ inp, int off)
{
  const int j = threadIdx.x;
  if (j >= NC) return;
  const int r0 = blockIdx.x * 128;
  float s = 0.f;
  for (int r = r0; r < r0 + 128; r++)
    s += fmaxf(X[(size_t)r * NC + j], Yp[(size_t)r * NC + j]);
  atomicAdd(&inp[off + j], s);
}

__global__ void fc1_k(const float* __restrict__ w1, const float* __restrict__ b1,
                      const float* __restrict__ inp, float* __restrict__ x)
{
  const int r = blockIdx.x * 256 + threadIdx.x;
  if (r >= 2000) return;
  float s = b1[r];
  const float* wr = w1 + (size_t)r * 600;
  for (int k = 0; k < 600; k++) s += wr[k] * inp[k];
  x[r] = fmaxf(s, 0.f);
}

__global__ void fc2_k(const float* __restrict__ x, const float* __restrict__ w2,
                      const float* __restrict__ b2, float* __restrict__ outp)
{
  const int tid = threadIdx.x;
  float s = 0.f;
  for (int i = tid; i < 2000; i += 256) s += x[i] * w2[i];
#pragma unroll
  for (int off = 32; off > 0; off >>= 1) s += __shfl_down(s, off);
  __shared__ float red[4];
  if ((tid & 63) == 0) red[tid >> 6] = s;
  __syncthreads();
  if (tid == 0) outp[0] = red[0] + red[1] + red[2] + red[3] + b2[0];
}

// ---------------- launch --------------------------------------------------------
extern "C" void kernel_launch(void* const* d_in, const int* in_sizes, int n_in,
                              void* d_out, int out_size, void* d_ws, size_t ws_size,
                              hipStream_t stream)
{
  const float* in_solv  = (const float*)d_in[0];
  const float* in_solu  = (const float*)d_in[1];
  const float* solv_Wih = (const float*)d_in[2];
  const float* solv_Whh = (const float*)d_in[3];
  const float* solv_bih = (const float*)d_in[4];
  const float* solv_bhh = (const float*)d_in[5];
  const float* solu_Wih = (const float*)d_in[6];
  const float* solu_Whh = (const float*)d_in[7];
  const float* solu_bih = (const float*)d_in[8];
  const float* solu_bhh = (const float*)d_in[9];
  const float* fc1_w = (const float*)d_in[10];
  const float* fc1_b = (const float*)d_in[11];
  const float* fc2_w = (const float*)d_in[12];
  const float* fc2_b = (const float*)d_in[13];
  float* outp = (float*)d_out;
  float* ws = (float*)d_ws;

  // ---- workspace layout (float offsets); peak 16,067,200 fl < prior 17.2M ----
  // off_P:  Wihh (819,200 fl) early -> Pb fp32 late (Wihh dead after xg_mfma l1)
  // off_xg: xg (9,830,400 fl) -> AH fp16 (8,388,608 fl) + HhT/GhT (655,360 fl)
  // off_L0: Avh/Auh fp16 -> Hh/Gh fp16 (pads inherited from conv_x zeros)
  // off_HG: L0vh/L0uh fp16 (pads pre-zeroed) -> Hb/Gb fp32 (after xg_mfma l1)
  constexpr size_t off_P   = 0;
  constexpr size_t off_Q   = 1228800;
  constexpr size_t off_inp = 2457600;   // 640
  constexpr size_t off_x   = 2458240;   // 2048
  constexpr size_t off_il  = 2460288;   // 4096
  constexpr size_t off_xg  = 2468480;
  constexpr size_t off_L0  = off_xg + (size_t)4 * 2457600;   // 12,298,880
  constexpr size_t off_HG  = off_L0 + 1310720;               // 13,609,600

  float*  xg   = ws + off_xg;
  float*  Hb   = ws + off_HG;
  float*  Gb   = Hb + 1228800;
  float*  Pb   = ws + off_P;
  float*  Qb   = ws + off_Q;
  float*  inp  = ws + off_inp;
  float*  xf   = ws + off_x;
  float*  il   = ws + off_il;
  __half* Wihh = (__half*)(ws + off_P);
  __half* Avh  = (__half*)(ws + off_L0);
  __half* Auh  = Avh + 4096 * 320;
  __half* L0vh = (__half*)(ws + off_HG);
  __half* L0uh = L0vh + 4096 * 320;
  __half* Hh   = (__half*)(ws + off_L0);   // reuses Avh/Auh space (dead)
  __half* Gh   = Hh + 4096 * 320;
  __half* AH   = (__half*)(ws + off_xg);   // after scans (xg dead)
  __half* HhT  = AH + (size_t)4096 * 4096;
  __half* GhT  = HhT + 320 * 4096;

  // ---- prep: zero L0vh/L0uh pads, convert weights + inputs to fp16 ----
  zero_f<<<5120, 256, 0, stream>>>(ws + off_HG, 1310720);
  conv_w<<<(8 * 640 * 320 + 255) / 256, 256, 0, stream>>>(solv_Wih, solu_Wih, Wihh);
  conv_x<<<5120, 256, 0, stream>>>(in_solv, Avh, 4096);
  conv_x<<<5120, 256, 0, stream>>>(in_solu, Auh, 4096);

  // ---- layer 0 (scan writes fp16 L0vh/L0uh directly; no fp32 out) ----
  xg_mfma<<<dim3(64, 4), 256, 0, stream>>>(Avh, Auh, Wihh,
      solv_bih, solv_bhh, solu_bih, solu_bhh, xg, 0);
  lstm_scan<<<4, 512, 0, stream>>>(solv_Whh, solu_Whh, xg,
      nullptr, nullptr, L0vh, L0uh, 0, 0);

  // ---- layer 1 (scan writes fp32 Hb/Gb + fp16 Hh/Gh) ----
  xg_mfma<<<dim3(64, 4), 256, 0, stream>>>(L0vh, L0uh, Wihh + (size_t)4 * 640 * 320,
      solv_bih, solv_bhh, solu_bih, solu_bhh, xg, 1);
  lstm_scan<<<4, 512, 0, stream>>>(solv_Whh, solu_Whh, xg,
      Hb, Gb, Hh, Gh, 1, 1);

  // ---- attention: S once (fp16), rowsum, scale, P/Q combined ----
  conv_t<<<5120, 256, 0, stream>>>(Hb, HhT);
  conv_t<<<5120, 256, 0, stream>>>(Gb, GhT);
  s_gemm<<<dim3(64, 4), 256, 0, stream>>>(Hh, Gh, AH);
  rowsum_k<<<4096, 256, 0, stream>>>(AH, il);
  scale_k<<<8192, 256, 0, stream>>>(AH, il);
  pq_mfma<<<128, 256, 0, stream>>>(AH, GhT, HhT, Pb, Qb);

  // ---- tail ----
  zero_f<<<3, 256, 0, stream>>>(inp, 640);
  reduce_uv<<<32, 320, 0, stream>>>(Hb, Pb, inp, 0);
  reduce_uv<<<32, 320, 0, stream>>>(Gb, Qb, inp, 300);
  fc1_k<<<8, 256, 0, stream>>>(fc1_w, fc1_b, inp, xf);
  fc2_k<<<1, 256, 0, stream>>>(xf, fc2_w, fc2_b, outp);
}

// Round 2
// 8451.753 us; speedup vs baseline: 1.0502x; 1.0502x over previous
//
#include <hip/hip_runtime.h>
#include <hip/hip_fp16.h>
#include <cstddef>

#define T_LEN 4096
#define HID 150
#define G4 600
#define NC 300

typedef __attribute__((ext_vector_type(8))) short bf16x8;      // 8 bf16 = 4 VGPRs
typedef __attribute__((ext_vector_type(8))) _Float16 f16x8;    // 8 fp16 = 4 VGPRs
typedef __attribute__((ext_vector_type(4))) float f32x4;

// raw barrier: waits LDS ops only, leaves global loads/stores in flight
__device__ __forceinline__ void barrier_lgkm() {
  asm volatile("s_waitcnt lgkmcnt(0)\n\ts_barrier" ::: "memory");
}

__device__ __forceinline__ float fsig(float x) {
  return __builtin_amdgcn_rcpf(1.f + __expf(-x));
}
__device__ __forceinline__ float ftanh(float x) {
  float ax = fabsf(x);
  float e = __expf(2.f * ax);
  float t = 1.f - 2.f * __builtin_amdgcn_rcpf(e + 1.f);
  return copysignf(t, x);
}
__device__ __forceinline__ unsigned short f2bf(float f) {  // RNE fp32->bf16
  unsigned u = __builtin_bit_cast(unsigned, f);
  u += 0x7fff + ((u >> 16) & 1);
  return (unsigned short)(u >> 16);
}

// ---------------- LSTM scan via MFMA: padded gate-major layout (r10) -----------
// r3 (two-phase, 1743 cyc/step) needed a g_s LDS all-to-all because gate
// stride 150 isn't 16-aligned. r10 computes g in GATE-MAJOR PADDED layout
// gp[4][160] by permuting Whh rows into the B-fragments at setup (free):
// tile T = 10*gt + wv covers gate gt of units 16wv..16wv+15. After the MFMAs
// lane ln<16 of wave wv holds ALL FOUR gate pre-activations of unit
// u=16wv+ln in acc[0..3][0] -> no g_s buffer, no exchange barrier, direct
// register indexing (no divergent select - r9's mistake). 10 waves (640 thr),
// 20 MFMA/wave, h double-buffered, ONE barrier/step. All LDS patterns are
// r3's measured-conflict-free ones: af read by 4 lanes/wave, 2B adjacent
// h-writes, B-frags in registers. r9's broadcast-B + scatter (524K conflicts,
// 2361 cyc) reverted.
__global__ __launch_bounds__(640, 3) void lstm_scan(
    const float* __restrict__ whh_solv, const float* __restrict__ whh_solu,
    const float* __restrict__ xg_base,
    float* __restrict__ o32v, float* __restrict__ o32u,
    __half* __restrict__ o16v, __half* __restrict__ o16u, int layer, int w32)
{
  __shared__ __align__(16) unsigned short hbuf[2][160];  // bf16 h, double-buffered
  const int c = blockIdx.x;
  const int net = c >> 1, dir = c & 1;
  const float* Whh = (net ? whh_solu : whh_solv) + (size_t)(layer * 2 + dir) * (G4 * HID);
  const float* xg = xg_base + (size_t)c * T_LEN * G4;
  float* out32 = (net ? o32u : o32v) + dir * HID;     // row stride NC (if w32)
  __half* out16 = (net ? o16u : o16v) + dir * HID;    // row stride 320
  const int tid = threadIdx.x;
  const int lane = tid & 63, wv = tid >> 6;           // wv in [0,10)
  const int lrow = lane & 15, lq = lane >> 4;

  // B-frags for tile T=10*gt+wv: col lrow -> unit un=16wv+lrow, gate gt.
  // B[k][lrow] = Whh[gt*150 + un][k]; zero-padded (un>=150 or k>=150).
  bf16x8 wfr[4][5];  // [gt][kk]
  const int un = 16 * wv + lrow;
#pragma unroll
  for (int gt = 0; gt < 4; gt++) {
#pragma unroll
    for (int kk = 0; kk < 5; kk++) {
      bf16x8 b;
#pragma unroll
      for (int i = 0; i < 8; i++) {
        const int k = kk * 32 + lq * 8 + i;
        const float v = (un < HID && k < HID) ? Whh[(size_t)(gt * HID + un) * HID + k] : 0.f;
        b[i] = (short)f2bf(v);
      }
      wfr[gt][kk] = b;
    }
  }
  if (tid < 160) hbuf[0][tid] = 0;

  // gate lane (lane<16) owns unit u = 16wv+lane; 10 waves x 16 lanes = 160
  const int u = 16 * wv + lane;
  const bool gl = (lane < 16);
  const bool act = gl && (u < HID);
  float cst = 0.f;
  float xr0 = 0.f, xr1 = 0.f, xr2 = 0.f, xr3 = 0.f;
  if (act) {
    const int t0 = dir ? (T_LEN - 1) : 0;
    const float* xgr = xg + (size_t)t0 * G4 + u;
    xr0 = xgr[0]; xr1 = xgr[HID]; xr2 = xgr[2 * HID]; xr3 = xgr[3 * HID];
  }
  barrier_lgkm();

  for (int s = 0; s < T_LEN; s++) {
    const int t = dir ? (T_LEN - 1 - s) : s;
    const unsigned short* hc = hbuf[s & 1];
    unsigned short* hn = hbuf[(s & 1) ^ 1];
    // A-frags: row0 = h, rows 1-15 zero -> only lanes with lrow==0 load (4/wave)
    bf16x8 af[5];
#pragma unroll
    for (int kk = 0; kk < 5; kk++) {
      bf16x8 a = {0, 0, 0, 0, 0, 0, 0, 0};
      if (lrow == 0) a = *(const bf16x8*)&hc[kk * 32 + lq * 8];
      af[kk] = a;
    }
    f32x4 acc[4];
#pragma unroll
    for (int gt = 0; gt < 4; gt++) acc[gt] = (f32x4){0.f, 0.f, 0.f, 0.f};
#pragma unroll
    for (int kk = 0; kk < 5; kk++)
#pragma unroll
      for (int gt = 0; gt < 4; gt++)
        acc[gt] = __builtin_amdgcn_mfma_f32_16x16x32_bf16(af[kk], wfr[gt][kk], acc[gt], 0, 0, 0);
    // lane<16: acc[gt][0] = gate gt of unit u. Gates fully in-register.
    if (gl) {
      float gi = acc[0][0] + xr0, gf = acc[1][0] + xr1;
      float gg = acc[2][0] + xr2, go = acc[3][0] + xr3;
      if (s + 1 < T_LEN && act) {  // prefetch next xg row (in flight past barrier)
        const int tn = dir ? (T_LEN - 2 - s) : (s + 1);
        const float* xgr = xg + (size_t)tn * G4 + u;
        xr0 = xgr[0]; xr1 = xgr[HID]; xr2 = xgr[2 * HID]; xr3 = xgr[3 * HID];
      }
      const float iv = fsig(gi), fv = fsig(gf), gv = ftanh(gg), ov = fsig(go);
      cst = fv * cst + iv * gv;
      const float hv = ov * ftanh(cst);
      unsigned short hw = 0;               // pad units (u>=150) stay zero
      if (act) {
        hw = f2bf(hv);                     // matvec input rounded; c/h state fp32
        out16[(size_t)t * 320 + u] = __float2half(hv);
        if (w32) out32[(size_t)t * NC + u] = hv;
      }
      hn[u] = hw;                          // 2B adjacent writes: 0 conflicts in r3
    }
    barrier_lgkm();   // ONE barrier/step: hn becomes hc of step s+1
  }
}

// ---------------- fp32 -> fp16 conversion helpers ------------------------------
// Wihh[8][640][320]: slot s = l*4 + net*2 + dir, zero-padded rows/cols
__global__ void conv_w(const float* __restrict__ wv, const float* __restrict__ wu,
                       __half* __restrict__ dst)
{
  const int gid = blockIdx.x * 256 + threadIdx.x;
  if (gid >= 8 * 640 * 320) return;
  const int k = gid % 320, j = (gid / 320) % 640, s = gid / (320 * 640);
  const int l = s >> 2, net = (s >> 1) & 1, dir = s & 1;
  float v = 0.f;
  if (j < G4 && k < NC) {
    const float* src = (net ? wu : wv) + (size_t)(l * 2 + dir) * (G4 * NC);
    v = src[(size_t)j * NC + k];
  }
  dst[gid] = __float2half(v);
}

// X fp32 [rows][300] -> Xh fp16 [rows][320] zero-padded
__global__ void conv_x(const float* __restrict__ src, __half* __restrict__ dst, int rows)
{
  const int gid = blockIdx.x * 256 + threadIdx.x;
  if (gid >= rows * 320) return;
  const int k = gid % 320, m = gid / 320;
  dst[gid] = __float2half(k < NC ? src[(size_t)m * NC + k] : 0.f);
}

// X fp32 [4096][300] -> XT fp16 [320][4096] (rows >= 300 zeroed)
__global__ void conv_t(const float* __restrict__ src, __half* __restrict__ dst)
{
  const int gid = blockIdx.x * 256 + threadIdx.x;
  if (gid >= 320 * 4096) return;
  const int m = gid % 4096, f = gid / 4096;
  dst[gid] = __float2half(f < NC ? src[(size_t)m * NC + f] : 0.f);
}

__global__ void zero_f(float* __restrict__ p, int n) {
  const int i = blockIdx.x * 256 + threadIdx.x;
  if (i < n) p[i] = 0.f;
}

// ---------------- xg = X @ Wih^T + b via fp16 MFMA -----------------------------
// grid (64 m-blocks, 4 chains), block 256 (4 waves, 16 rows each). N=640, K=320.
__global__ __launch_bounds__(256) void xg_mfma(
    const __half* __restrict__ Av, const __half* __restrict__ Au,
    const __half* __restrict__ W,   // Wihh + layer*4*640*320
    const float* __restrict__ bihv, const float* __restrict__ bhhv,
    const float* __restrict__ bihu, const float* __restrict__ bhhu,
    float* __restrict__ xg, int layer)
{
  const int tid = threadIdx.x;
  const int lane = tid & 63, wv = tid >> 6;
  const int ln = lane & 15, q = lane >> 4;
  const int chain = blockIdx.y;
  const __half* A = (chain >= 2) ? Au : Av;
  const __half* Wc = W + (size_t)chain * 640 * 320;
  const float* bi = ((chain >= 2) ? bihu : bihv) + (size_t)(layer * 2 + (chain & 1)) * G4;
  const float* bh = ((chain >= 2) ? bhhu : bhhv) + (size_t)(layer * 2 + (chain & 1)) * G4;
  float* C = xg + (size_t)chain * T_LEN * G4;
  const int m0 = blockIdx.x * 64 + wv * 16;
  const __half* Arow = A + (size_t)(m0 + ln) * 320;

  for (int nc = 0; nc < 4; nc++) {       // 4 chunks x 160 cols
    f32x4 acc[10];
#pragma unroll
    for (int j = 0; j < 10; j++) acc[j] = (f32x4){0.f, 0.f, 0.f, 0.f};
    for (int kk = 0; kk < 10; kk++) {
      const f16x8 afr = *(const f16x8*)(Arow + kk * 32 + q * 8);
#pragma unroll
      for (int j = 0; j < 10; j++) {
        const int n = nc * 160 + j * 16 + ln;
        const f16x8 bfr = *(const f16x8*)(Wc + (size_t)n * 320 + kk * 32 + q * 8);
        acc[j] = __builtin_amdgcn_mfma_f32_16x16x32_f16(afr, bfr, acc[j], 0, 0, 0);
      }
    }
#pragma unroll
    for (int j = 0; j < 10; j++) {
      const int n = nc * 160 + j * 16 + ln;
      if (n < G4) {
        const float bias = bi[n] + bh[n];
#pragma unroll
        for (int r = 0; r < 4; r++)
          C[(size_t)(m0 + q * 4 + r) * G4 + n] = acc[j][r] + bias;
      }
    }
  }
}

// ------- S GEMM: AH[m][n] = fp16(Hh[m] . Gh[n]), raw scores (no exp) -----------
// grid (64 m-blocks, 4 n-quadrants), block 256. Softmax shift/normalization
// happens later on the ROUNDED values (self-consistent).
__global__ __launch_bounds__(256) void s_gemm(
    const __half* __restrict__ Hh, const __half* __restrict__ Gh,
    __half* __restrict__ AH)
{
  const int tid = threadIdx.x;
  const int lane = tid & 63, wv = tid >> 6;
  const int ln = lane & 15, q = lane >> 4;
  const int m0 = blockIdx.x * 64 + wv * 16;
  const __half* Arow = Hh + (size_t)(m0 + ln) * 320;
  f16x8 afr[10];
#pragma unroll
  for (int kk = 0; kk < 10; kk++) afr[kk] = *(const f16x8*)(Arow + kk * 32 + q * 8);
  const int nt0 = blockIdx.y * 64;
  for (int nt = 0; nt < 64; nt++) {
    const int n = 16 * (nt0 + nt) + ln;
    const __half* Brow = Gh + (size_t)n * 320;
    f32x4 acc = (f32x4){0.f, 0.f, 0.f, 0.f};
#pragma unroll
    for (int kk = 0; kk < 10; kk++) {
      const f16x8 bfr = *(const f16x8*)(Brow + kk * 32 + q * 8);
      acc = __builtin_amdgcn_mfma_f32_16x16x32_f16(afr[kk], bfr, acc, 0, 0, 0);
    }
#pragma unroll
    for (int r = 0; r < 4; r++)
      AH[(size_t)(m0 + q * 4 + r) * 4096 + n] = __float2half(acc[r]);
  }
}

// ------- rowsum: il[m] = 1 / sum_n exp(S[m][n] - 30)  (one block per row) ------
__global__ __launch_bounds__(256) void rowsum_k(const __half* __restrict__ AH,
                                                float* __restrict__ il)
{
  const int m = blockIdx.x, tid = threadIdx.x;
  const __half* row = AH + (size_t)m * 4096;
  float s = 0.f;
  for (int i = tid * 8; i < 4096; i += 2048) {
    const f16x8 v = *(const f16x8*)(row + i);
#pragma unroll
    for (int j = 0; j < 8; j++) s += __expf(fminf((float)v[j] - 30.f, 80.f));
  }
#pragma unroll
  for (int off = 32; off > 0; off >>= 1) s += __shfl_down(s, off);
  __shared__ float red[4];
  if ((tid & 63) == 0) red[tid >> 6] = s;
  __syncthreads();
  if (tid == 0) il[m] = 1.f / (red[0] + red[1] + red[2] + red[3]);
}

// ------- scale: AH = fp16( exp(S-30) * il[m] ), in place -----------------------
__global__ __launch_bounds__(256) void scale_k(__half* __restrict__ AH,
                                               const float* __restrict__ il)
{
  const size_t gid = (size_t)blockIdx.x * 256 + threadIdx.x;  // f16x8 chunk id
  const int m = (int)(gid >> 9);                              // 512 chunks/row
  const float ilm = il[m];
  f16x8 v = *(f16x8*)(AH + gid * 8);
#pragma unroll
  for (int j = 0; j < 8; j++)
    v[j] = (_Float16)(__expf(fminf((float)v[j] - 30.f, 80.f)) * ilm);
  *(f16x8*)(AH + gid * 8) = v;
}

// ------- P = AH @ GhT' and Q = AH^T @ HhT' in ONE dispatch (128 blocks) --------
__global__ __launch_bounds__(256) void pq_mfma(
    const __half* __restrict__ AH, const __half* __restrict__ GhT,
    const __half* __restrict__ HhT,
    float* __restrict__ Pb, float* __restrict__ Qb)
{
  __shared__ __align__(16) _Float16 Ats[64][72];  // qt staging, pitch 144 B
  const int tid = threadIdx.x;
  const int lane = tid & 63, wv = tid >> 6;
  const int ln = lane & 15, q = lane >> 4;

  if (blockIdx.x < 64) {
    // ---- P part: M=4096 rows of AH, N=320(store 300), K=4096 ----
    const int m0 = blockIdx.x * 64 + wv * 16;
    const __half* Arow = AH + (size_t)(m0 + ln) * 4096;
    for (int nc = 0; nc < 2; nc++) {
      f32x4 acc[10];
#pragma unroll
      for (int j = 0; j < 10; j++) acc[j] = (f32x4){0.f, 0.f, 0.f, 0.f};
      for (int kk = 0; kk < 128; kk++) {
        const f16x8 afr = *(const f16x8*)(Arow + kk * 32 + q * 8);
#pragma unroll
        for (int j = 0; j < 10; j++) {
          const int n = nc * 160 + j * 16 + ln;
          const f16x8 bfr = *(const f16x8*)(GhT + (size_t)n * 4096 + kk * 32 + q * 8);
          acc[j] = __builtin_amdgcn_mfma_f32_16x16x32_f16(afr, bfr, acc[j], 0, 0, 0);
        }
      }
#pragma unroll
      for (int j = 0; j < 10; j++) {
        const int n = nc * 160 + j * 16 + ln;
        if (n < NC) {
#pragma unroll
          for (int r = 0; r < 4; r++)
            Pb[(size_t)(m0 + q * 4 + r) * NC + n] = acc[j][r];
        }
      }
    }
  } else {
    // ---- Q part: Q[j][f] = sum_i a[i][j] H[i][f]; a transposed via LDS ----
    const int j0 = (blockIdx.x - 64) * 64;
    f32x4 acc[20];
#pragma unroll
    for (int j = 0; j < 20; j++) acc[j] = (f32x4){0.f, 0.f, 0.f, 0.f};
    const int il8 = tid >> 2, j8 = (tid & 3) * 16;  // staging role
    for (int ic = 0; ic < 4096; ic += 64) {
      __syncthreads();
      {
        const __half* src = AH + (size_t)(ic + il8) * 4096 + j0 + j8;
        const f16x8 v0 = *(const f16x8*)src;
        const f16x8 v1 = *(const f16x8*)(src + 8);
#pragma unroll
        for (int jj = 0; jj < 8; jj++) Ats[j8 + jj][il8] = v0[jj];
#pragma unroll
        for (int jj = 0; jj < 8; jj++) Ats[j8 + 8 + jj][il8] = v1[jj];
      }
      __syncthreads();
#pragma unroll
      for (int s = 0; s < 2; s++) {
        const f16x8 afr = *(const f16x8*)&Ats[wv * 16 + ln][s * 32 + q * 8];
        const __half* bbase = HhT + ic + s * 32 + q * 8;
#pragma unroll
        for (int j = 0; j < 20; j++) {
          const f16x8 bfr = *(const f16x8*)(bbase + (size_t)(j * 16 + ln) * 4096);
          acc[j] = __builtin_amdgcn_mfma_f32_16x16x32_f16(afr, bfr, acc[j], 0, 0, 0);
        }
      }
    }
#pragma unroll
    for (int j = 0; j < 20; j++) {
      const int f = j * 16 + ln;
      if (f < NC) {
#pragma unroll
        for (int r = 0; r < 4; r++)
          Qb[(size_t)(j0 + wv * 16 + q * 4 + r) * NC + f] = acc[j][r];
      }
    }
  }
}

// ---------------- tail ---------------------------------------------------------
__global__ void reduce_uv(const float* __restrict__ X, const float* __restrict__ Yp,
                          float* __restrict__ inp, int off)
{
  const int j = threadIdx.x;
  if (j >= NC) return;
  const int r0 = blockIdx.x * 128;
  float s = 0.f;
  for (int r = r0; r < r0 + 128; r++)
    s += fmaxf(X[(size_t)r * NC + j], Yp[(size_t)r * NC + j]);
  atomicAdd(&inp[off + j], s);
}

__global__ void fc1_k(const float* __restrict__ w1, const float* __restrict__ b1,
                      const float* __restrict__ inp, float* __restrict__ x)
{
  const int r = blockIdx.x * 256 + threadIdx.x;
  if (r >= 2000) return;
  float s = b1[r];
  const float* wr = w1 + (size_t)r * 600;
  for (int k = 0; k < 600; k++) s += wr[k] * inp[k];
  x[r] = fmaxf(s, 0.f);
}

__global__ void fc2_k(const float* __restrict__ x, const float* __restrict__ w2,
                      const float* __restrict__ b2, float* __restrict__ outp)
{
  const int tid = threadIdx.x;
  float s = 0.f;
  for (int i = tid; i < 2000; i += 256) s += x[i] * w2[i];
#pragma unroll
  for (int off = 32; off > 0; off >>= 1) s += __shfl_down(s, off);
  __shared__ float red[4];
  if ((tid & 63) == 0) red[tid >> 6] = s;
  __syncthreads();
  if (tid == 0) outp[0] = red[0] + red[1] + red[2] + red[3] + b2[0];
}

// ---------------- launch --------------------------------------------------------
extern "C" void kernel_launch(void* const* d_in, const int* in_sizes, int n_in,
                              void* d_out, int out_size, void* d_ws, size_t ws_size,
                              hipStream_t stream)
{
  const float* in_solv  = (const float*)d_in[0];
  const float* in_solu  = (const float*)d_in[1];
  const float* solv_Wih = (const float*)d_in[2];
  const float* solv_Whh = (const float*)d_in[3];
  const float* solv_bih = (const float*)d_in[4];
  const float* solv_bhh = (const float*)d_in[5];
  const float* solu_Wih = (const float*)d_in[6];
  const float* solu_Whh = (const float*)d_in[7];
  const float* solu_bih = (const float*)d_in[8];
  const float* solu_bhh = (const float*)d_in[9];
  const float* fc1_w = (const float*)d_in[10];
  const float* fc1_b = (const float*)d_in[11];
  const float* fc2_w = (const float*)d_in[12];
  const float* fc2_b = (const float*)d_in[13];
  float* outp = (float*)d_out;
  float* ws = (float*)d_ws;

  // ---- workspace layout (float offsets); peak 16,067,200 fl < prior 17.2M ----
  // off_P:  Wihh (819,200 fl) early -> Pb fp32 late (Wihh dead after xg_mfma l1)
  // off_xg: xg (9,830,400 fl) -> AH fp16 (8,388,608 fl) + HhT/GhT (655,360 fl)
  // off_L0: Avh/Auh fp16 -> Hh/Gh fp16 (pads inherited from conv_x zeros)
  // off_HG: L0vh/L0uh fp16 (pads pre-zeroed) -> Hb/Gb fp32 (after xg_mfma l1)
  constexpr size_t off_P   = 0;
  constexpr size_t off_Q   = 1228800;
  constexpr size_t off_inp = 2457600;   // 640
  constexpr size_t off_x   = 2458240;   // 2048
  constexpr size_t off_il  = 2460288;   // 4096
  constexpr size_t off_xg  = 2468480;
  constexpr size_t off_L0  = off_xg + (size_t)4 * 2457600;   // 12,298,880
  constexpr size_t off_HG  = off_L0 + 1310720;               // 13,609,600

  float*  xg   = ws + off_xg;
  float*  Hb   = ws + off_HG;
  float*  Gb   = Hb + 1228800;
  float*  Pb   = ws + off_P;
  float*  Qb   = ws + off_Q;
  float*  inp  = ws + off_inp;
  float*  xf   = ws + off_x;
  float*  il   = ws + off_il;
  __half* Wihh = (__half*)(ws + off_P);
  __half* Avh  = (__half*)(ws + off_L0);
  __half* Auh  = Avh + 4096 * 320;
  __half* L0vh = (__half*)(ws + off_HG);
  __half* L0uh = L0vh + 4096 * 320;
  __half* Hh   = (__half*)(ws + off_L0);   // reuses Avh/Auh space (dead)
  __half* Gh   = Hh + 4096 * 320;
  __half* AH   = (__half*)(ws + off_xg);   // after scans (xg dead)
  __half* HhT  = AH + (size_t)4096 * 4096;
  __half* GhT  = HhT + 320 * 4096;

  // ---- prep: zero L0vh/L0uh pads, convert weights + inputs to fp16 ----
  zero_f<<<5120, 256, 0, stream>>>(ws + off_HG, 1310720);
  conv_w<<<(8 * 640 * 320 + 255) / 256, 256, 0, stream>>>(solv_Wih, solu_Wih, Wihh);
  conv_x<<<5120, 256, 0, stream>>>(in_solv, Avh, 4096);
  conv_x<<<5120, 256, 0, stream>>>(in_solu, Auh, 4096);

  // ---- layer 0 (scan writes fp16 L0vh/L0uh directly; no fp32 out) ----
  xg_mfma<<<dim3(64, 4), 256, 0, stream>>>(Avh, Auh, Wihh,
      solv_bih, solv_bhh, solu_bih, solu_bhh, xg, 0);
  lstm_scan<<<4, 640, 0, stream>>>(solv_Whh, solu_Whh, xg,
      nullptr, nullptr, L0vh, L0uh, 0, 0);

  // ---- layer 1 (scan writes fp32 Hb/Gb + fp16 Hh/Gh) ----
  xg_mfma<<<dim3(64, 4), 256, 0, stream>>>(L0vh, L0uh, Wihh + (size_t)4 * 640 * 320,
      solv_bih, solv_bhh, solu_bih, solu_bhh, xg, 1);
  lstm_scan<<<4, 640, 0, stream>>>(solv_Whh, solu_Whh, xg,
      Hb, Gb, Hh, Gh, 1, 1);

  // ---- attention: S once (fp16), rowsum, scale, P/Q combined ----
  conv_t<<<5120, 256, 0, stream>>>(Hb, HhT);
  conv_t<<<5120, 256, 0, stream>>>(Gb, GhT);
  s_gemm<<<dim3(64, 4), 256, 0, stream>>>(Hh, Gh, AH);
  rowsum_k<<<4096, 256, 0, stream>>>(AH, il);
  scale_k<<<8192, 256, 0, stream>>>(AH, il);
  pq_mfma<<<128, 256, 0, stream>>>(AH, GhT, HhT, Pb, Qb);

  // ---- tail ----
  zero_f<<<3, 256, 0, stream>>>(inp, 640);
  reduce_uv<<<32, 320, 0, stream>>>(Hb, Pb, inp, 0);
  reduce_uv<<<32, 320, 0, stream>>>(Gb, Qb, inp, 300);
  fc1_k<<<8, 256, 0, stream>>>(fc1_w, fc1_b, inp, xf);
  fc2_k<<<1, 256, 0, stream>>>(xf, fc2_w, fc2_b, outp);
}

// Round 3
// 6971.654 us; speedup vs baseline: 1.2731x; 1.2123x over previous
//
#include <hip/hip_runtime.h>
#include <hip/hip_fp16.h>
#include <cstddef>

#define T_LEN 4096
#define HID 150
#define G4 600
#define NC 300

typedef __attribute__((ext_vector_type(8))) short bf16x8;      // 8 bf16 = 4 VGPRs
typedef __attribute__((ext_vector_type(8))) _Float16 f16x8;    // 8 fp16 = 4 VGPRs
typedef __attribute__((ext_vector_type(4))) float f32x4;

// raw barrier: waits LDS ops only, leaves global loads/stores in flight
__device__ __forceinline__ void barrier_lgkm() {
  asm volatile("s_waitcnt lgkmcnt(0)\n\ts_barrier" ::: "memory");
}

__device__ __forceinline__ float fsig(float x) {
  return __builtin_amdgcn_rcpf(1.f + __expf(-x));
}
__device__ __forceinline__ float ftanh(float x) {
  float ax = fabsf(x);
  float e = __expf(2.f * ax);
  float t = 1.f - 2.f * __builtin_amdgcn_rcpf(e + 1.f);
  return copysignf(t, x);
}
__device__ __forceinline__ unsigned short f2bf(float f) {  // RNE fp32->bf16
  unsigned u = __builtin_bit_cast(unsigned, f);
  u += 0x7fff + ((u >> 16) & 1);
  return (unsigned short)(u >> 16);
}

// ---------------- LSTM scan via MFMA: r3 skeleton + surgical trims (r11) -------
// HISTORY (cyc/step): r3 two-phase=1743 BEST; r5 af-hoist=1854; r6 gate-permute
// =2439; r7 16-wave=1968; r8 1-barrier=1893; r9 bcast-B+select=2361 (524K LDS
// conflicts); r10 gate-major 10-wave 1-barrier=2231 (VALU spread to all waves).
// LAW: keep two-phase + 8 waves + gate work concentrated on 3 waves; barriers
// are NOT the bottleneck (refuted 3x: r8/r9/r10) - per-SIMD issue before the
// barrier is. r11 = r3 with ONLY issue-count trims, no structural change:
//  (a) gate-interleaved padded B (tile T=wv+8j -> gate T&3, units 16*(T>>2)+ln)
//      so g lands as g4[unit][4] and gate phase reads ONE ds_read_b128
//      (coalesced) instead of 4 strided ds_read_b32.
//  (b) running pointers (+-600/+-320/+-300) replace per-step 64-bit mults.
//  (c) w32 templated out of the layer-0 scan.
template <int W32>
__global__ __launch_bounds__(512, 2) void lstm_scan(
    const float* __restrict__ whh_solv, const float* __restrict__ whh_solu,
    const float* __restrict__ xg_base,
    float* __restrict__ o32v, float* __restrict__ o32u,
    __half* __restrict__ o16v, __half* __restrict__ o16u, int layer)
{
  __shared__ __align__(16) unsigned short h_bf[160];  // bf16 h, zeros beyond 150
  __shared__ __align__(16) float g4[160][4];          // unit-major, gate-minor
  const int c = blockIdx.x;
  const int net = c >> 1, dir = c & 1;
  const float* Whh = (net ? whh_solu : whh_solv) + (size_t)(layer * 2 + dir) * (G4 * HID);
  const float* xg = xg_base + (size_t)c * T_LEN * G4;
  float* out32 = (net ? o32u : o32v) + dir * HID;     // row stride NC (if W32)
  __half* out16 = (net ? o16u : o16v) + dir * HID;    // row stride 320
  const int tid = threadIdx.x;
  const int lane = tid & 63, wv = tid >> 6;
  const int lrow = lane & 15, lq = lane >> 4;  // frag row & k-quad

  // B-fragments, gate-interleaved tiles: T=wv+8j, gt=T&3, uw=T>>2.
  // B[k][lrow] = Whh[gt*150 + (16*uw+lrow)][k]; zero-padded.
  bf16x8 bfr[5][5];  // [j][kk]
#pragma unroll
  for (int j = 0; j < 5; j++) {
    const int T = wv + 8 * j, gt = T & 3, uw = T >> 2;
    const int un = 16 * uw + lrow;
#pragma unroll
    for (int kk = 0; kk < 5; kk++) {
      bf16x8 b;
#pragma unroll
      for (int i = 0; i < 8; i++) {
        const int k = kk * 32 + lq * 8 + i;
        const float v = (un < HID && k < HID) ? Whh[(size_t)(gt * HID + un) * HID + k] : 0.f;
        b[i] = (short)f2bf(v);
      }
      bfr[j][kk] = b;
    }
  }
  if (tid < 160) h_bf[tid] = 0;

  const int t0 = dir ? (T_LEN - 1) : 0;
  const int d16 = dir ? -320 : 320;
  const int d32 = dir ? -NC : NC;
  const int dxg = dir ? -G4 : G4;
  float cst = 0.f;
  float xr0 = 0.f, xr1 = 0.f, xr2 = 0.f, xr3 = 0.f;
  const float* xgp = xg + (size_t)t0 * G4 + tid;   // gate lanes only
  __half* o16p = out16 + (size_t)t0 * 320 + tid;
  float* o32p = out32 + (size_t)t0 * NC + tid;
  if (tid < HID) { xr0 = xgp[0]; xr1 = xgp[HID]; xr2 = xgp[2 * HID]; xr3 = xgp[3 * HID]; }
  barrier_lgkm();

  for (int s = 0; s < T_LEN; s++) {
    // A-frags: row0 = h_bf, rows 1-15 zero -> only lanes with lrow==0 load
    bf16x8 af[5];
#pragma unroll
    for (int kk = 0; kk < 5; kk++) {
      bf16x8 a = {0, 0, 0, 0, 0, 0, 0, 0};
      if (lrow == 0) a = *(const bf16x8*)&h_bf[kk * 32 + lq * 8];
      af[kk] = a;
    }
    f32x4 acc[5];
#pragma unroll
    for (int j = 0; j < 5; j++) acc[j] = (f32x4){0.f, 0.f, 0.f, 0.f};
#pragma unroll
    for (int kk = 0; kk < 5; kk++)
#pragma unroll
      for (int j = 0; j < 5; j++)
        acc[j] = __builtin_amdgcn_mfma_f32_16x16x32_bf16(af[kk], bfr[j][kk], acc[j], 0, 0, 0);
    // D row0 lives in lanes 0-15, reg 0: scatter into unit-major g4.
    // Banks (4*ln+gt)&31: ln vs ln+8 alias -> 2-way conflict = free (m136).
    if (lane < 16) {
#pragma unroll
      for (int j = 0; j < 5; j++) {
        const int T = wv + 8 * j, gt = T & 3, uw = T >> 2;
        g4[16 * uw + lane][gt] = acc[j][0];
      }
    }
    barrier_lgkm();
    if (tid < HID) {
      const f32x4 g = *(const f32x4*)&g4[tid][0];   // ONE b128, coalesced
      float gi = xr0 + g[0];
      float gf = xr1 + g[1];
      float gg = xr2 + g[2];
      float go = xr3 + g[3];
      xgp += dxg;
      if (s + 1 < T_LEN) {  // prefetch next xg row (stays in flight past barrier)
        xr0 = xgp[0]; xr1 = xgp[HID]; xr2 = xgp[2 * HID]; xr3 = xgp[3 * HID];
      }
      const float iv = fsig(gi), fv = fsig(gf), gv = ftanh(gg), ov = fsig(go);
      cst = fv * cst + iv * gv;
      const float hv = ov * ftanh(cst);
      h_bf[tid] = f2bf(hv);      // matvec input rounded; c/h state stays fp32
      *o16p = __float2half(hv);
      o16p += d16;
      if (W32) { *o32p = hv; o32p += d32; }
    }
    barrier_lgkm();
  }
}

// ---------------- fp32 -> fp16 conversion helpers ------------------------------
// Wihh[8][640][320]: slot s = l*4 + net*2 + dir, zero-padded rows/cols
__global__ void conv_w(const float* __restrict__ wv, const float* __restrict__ wu,
                       __half* __restrict__ dst)
{
  const int gid = blockIdx.x * 256 + threadIdx.x;
  if (gid >= 8 * 640 * 320) return;
  const int k = gid % 320, j = (gid / 320) % 640, s = gid / (320 * 640);
  const int l = s >> 2, net = (s >> 1) & 1, dir = s & 1;
  float v = 0.f;
  if (j < G4 && k < NC) {
    const float* src = (net ? wu : wv) + (size_t)(l * 2 + dir) * (G4 * NC);
    v = src[(size_t)j * NC + k];
  }
  dst[gid] = __float2half(v);
}

// X fp32 [rows][300] -> Xh fp16 [rows][320] zero-padded
__global__ void conv_x(const float* __restrict__ src, __half* __restrict__ dst, int rows)
{
  const int gid = blockIdx.x * 256 + threadIdx.x;
  if (gid >= rows * 320) return;
  const int k = gid % 320, m = gid / 320;
  dst[gid] = __float2half(k < NC ? src[(size_t)m * NC + k] : 0.f);
}

// X fp32 [4096][300] -> XT fp16 [320][4096] (rows >= 300 zeroed)
__global__ void conv_t(const float* __restrict__ src, __half* __restrict__ dst)
{
  const int gid = blockIdx.x * 256 + threadIdx.x;
  if (gid >= 320 * 4096) return;
  const int m = gid % 4096, f = gid / 4096;
  dst[gid] = __float2half(f < NC ? src[(size_t)m * NC + f] : 0.f);
}

__global__ void zero_f(float* __restrict__ p, int n) {
  const int i = blockIdx.x * 256 + threadIdx.x;
  if (i < n) p[i] = 0.f;
}

// ---------------- xg = X @ Wih^T + b via fp16 MFMA -----------------------------
// grid (64 m-blocks, 4 chains), block 256 (4 waves, 16 rows each). N=640, K=320.
__global__ __launch_bounds__(256) void xg_mfma(
    const __half* __restrict__ Av, const __half* __restrict__ Au,
    const __half* __restrict__ W,   // Wihh + layer*4*640*320
    const float* __restrict__ bihv, const float* __restrict__ bhhv,
    const float* __restrict__ bihu, const float* __restrict__ bhhu,
    float* __restrict__ xg, int layer)
{
  const int tid = threadIdx.x;
  const int lane = tid & 63, wv = tid >> 6;
  const int ln = lane & 15, q = lane >> 4;
  const int chain = blockIdx.y;
  const __half* A = (chain >= 2) ? Au : Av;
  const __half* Wc = W + (size_t)chain * 640 * 320;
  const float* bi = ((chain >= 2) ? bihu : bihv) + (size_t)(layer * 2 + (chain & 1)) * G4;
  const float* bh = ((chain >= 2) ? bhhu : bhhv) + (size_t)(layer * 2 + (chain & 1)) * G4;
  float* C = xg + (size_t)chain * T_LEN * G4;
  const int m0 = blockIdx.x * 64 + wv * 16;
  const __half* Arow = A + (size_t)(m0 + ln) * 320;

  for (int nc = 0; nc < 4; nc++) {       // 4 chunks x 160 cols
    f32x4 acc[10];
#pragma unroll
    for (int j = 0; j < 10; j++) acc[j] = (f32x4){0.f, 0.f, 0.f, 0.f};
    for (int kk = 0; kk < 10; kk++) {
      const f16x8 afr = *(const f16x8*)(Arow + kk * 32 + q * 8);
#pragma unroll
      for (int j = 0; j < 10; j++) {
        const int n = nc * 160 + j * 16 + ln;
        const f16x8 bfr = *(const f16x8*)(Wc + (size_t)n * 320 + kk * 32 + q * 8);
        acc[j] = __builtin_amdgcn_mfma_f32_16x16x32_f16(afr, bfr, acc[j], 0, 0, 0);
      }
    }
#pragma unroll
    for (int j = 0; j < 10; j++) {
      const int n = nc * 160 + j * 16 + ln;
      if (n < G4) {
        const float bias = bi[n] + bh[n];
#pragma unroll
        for (int r = 0; r < 4; r++)
          C[(size_t)(m0 + q * 4 + r) * G4 + n] = acc[j][r] + bias;
      }
    }
  }
}

// ------- S GEMM: AH[m][n] = fp16(Hh[m] . Gh[n]), raw scores (no exp) -----------
// grid (64 m-blocks, 4 n-quadrants), block 256. Softmax shift/normalization
// happens later on the ROUNDED values (self-consistent).
__global__ __launch_bounds__(256) void s_gemm(
    const __half* __restrict__ Hh, const __half* __restrict__ Gh,
    __half* __restrict__ AH)
{
  const int tid = threadIdx.x;
  const int lane = tid & 63, wv = tid >> 6;
  const int ln = lane & 15, q = lane >> 4;
  const int m0 = blockIdx.x * 64 + wv * 16;
  const __half* Arow = Hh + (size_t)(m0 + ln) * 320;
  f16x8 afr[10];
#pragma unroll
  for (int kk = 0; kk < 10; kk++) afr[kk] = *(const f16x8*)(Arow + kk * 32 + q * 8);
  const int nt0 = blockIdx.y * 64;
  for (int nt = 0; nt < 64; nt++) {
    const int n = 16 * (nt0 + nt) + ln;
    const __half* Brow = Gh + (size_t)n * 320;
    f32x4 acc = (f32x4){0.f, 0.f, 0.f, 0.f};
#pragma unroll
    for (int kk = 0; kk < 10; kk++) {
      const f16x8 bfr = *(const f16x8*)(Brow + kk * 32 + q * 8);
      acc = __builtin_amdgcn_mfma_f32_16x16x32_f16(afr[kk], bfr, acc, 0, 0, 0);
    }
#pragma unroll
    for (int r = 0; r < 4; r++)
      AH[(size_t)(m0 + q * 4 + r) * 4096 + n] = __float2half(acc[r]);
  }
}

// ------- rowsum: il[m] = 1 / sum_n exp(S[m][n] - 30)  (one block per row) ------
__global__ __launch_bounds__(256) void rowsum_k(const __half* __restrict__ AH,
                                                float* __restrict__ il)
{
  const int m = blockIdx.x, tid = threadIdx.x;
  const __half* row = AH + (size_t)m * 4096;
  float s = 0.f;
  for (int i = tid * 8; i < 4096; i += 2048) {
    const f16x8 v = *(const f16x8*)(row + i);
#pragma unroll
    for (int j = 0; j < 8; j++) s += __expf(fminf((float)v[j] - 30.f, 80.f));
  }
#pragma unroll
  for (int off = 32; off > 0; off >>= 1) s += __shfl_down(s, off);
  __shared__ float red[4];
  if ((tid & 63) == 0) red[tid >> 6] = s;
  __syncthreads();
  if (tid == 0) il[m] = 1.f / (red[0] + red[1] + red[2] + red[3]);
}

// ------- scale: AH = fp16( exp(S-30) * il[m] ), in place -----------------------
__global__ __launch_bounds__(256) void scale_k(__half* __restrict__ AH,
                                               const float* __restrict__ il)
{
  const size_t gid = (size_t)blockIdx.x * 256 + threadIdx.x;  // f16x8 chunk id
  const int m = (int)(gid >> 9);                              // 512 chunks/row
  const float ilm = il[m];
  f16x8 v = *(f16x8*)(AH + gid * 8);
#pragma unroll
  for (int j = 0; j < 8; j++)
    v[j] = (_Float16)(__expf(fminf((float)v[j] - 30.f, 80.f)) * ilm);
  *(f16x8*)(AH + gid * 8) = v;
}

// ------- P = AH @ GhT' and Q = AH^T @ HhT' in ONE dispatch (128 blocks) --------
__global__ __launch_bounds__(256) void pq_mfma(
    const __half* __restrict__ AH, const __half* __restrict__ GhT,
    const __half* __restrict__ HhT,
    float* __restrict__ Pb, float* __restrict__ Qb)
{
  __shared__ __align__(16) _Float16 Ats[64][72];  // qt staging, pitch 144 B
  const int tid = threadIdx.x;
  const int lane = tid & 63, wv = tid >> 6;
  const int ln = lane & 15, q = lane >> 4;

  if (blockIdx.x < 64) {
    // ---- P part: M=4096 rows of AH, N=320(store 300), K=4096 ----
    const int m0 = blockIdx.x * 64 + wv * 16;
    const __half* Arow = AH + (size_t)(m0 + ln) * 4096;
    for (int nc = 0; nc < 2; nc++) {
      f32x4 acc[10];
#pragma unroll
      for (int j = 0; j < 10; j++) acc[j] = (f32x4){0.f, 0.f, 0.f, 0.f};
      for (int kk = 0; kk < 128; kk++) {
        const f16x8 afr = *(const f16x8*)(Arow + kk * 32 + q * 8);
#pragma unroll
        for (int j = 0; j < 10; j++) {
          const int n = nc * 160 + j * 16 + ln;
          const f16x8 bfr = *(const f16x8*)(GhT + (size_t)n * 4096 + kk * 32 + q * 8);
          acc[j] = __builtin_amdgcn_mfma_f32_16x16x32_f16(afr, bfr, acc[j], 0, 0, 0);
        }
      }
#pragma unroll
      for (int j = 0; j < 10; j++) {
        const int n = nc * 160 + j * 16 + ln;
        if (n < NC) {
#pragma unroll
          for (int r = 0; r < 4; r++)
            Pb[(size_t)(m0 + q * 4 + r) * NC + n] = acc[j][r];
        }
      }
    }
  } else {
    // ---- Q part: Q[j][f] = sum_i a[i][j] H[i][f]; a transposed via LDS ----
    const int j0 = (blockIdx.x - 64) * 64;
    f32x4 acc[20];
#pragma unroll
    for (int j = 0; j < 20; j++) acc[j] = (f32x4){0.f, 0.f, 0.f, 0.f};
    const int il8 = tid >> 2, j8 = (tid & 3) * 16;  // staging role
    for (int ic = 0; ic < 4096; ic += 64) {
      __syncthreads();
      {
        const __half* src = AH + (size_t)(ic + il8) * 4096 + j0 + j8;
        const f16x8 v0 = *(const f16x8*)src;
        const f16x8 v1 = *(const f16x8*)(src + 8);
#pragma unroll
        for (int jj = 0; jj < 8; jj++) Ats[j8 + jj][il8] = v0[jj];
#pragma unroll
        for (int jj = 0; jj < 8; jj++) Ats[j8 + 8 + jj][il8] = v1[jj];
      }
      __syncthreads();
#pragma unroll
      for (int s = 0; s < 2; s++) {
        const f16x8 afr = *(const f16x8*)&Ats[wv * 16 + ln][s * 32 + q * 8];
        const __half* bbase = HhT + ic + s * 32 + q * 8;
#pragma unroll
        for (int j = 0; j < 20; j++) {
          const f16x8 bfr = *(const f16x8*)(bbase + (size_t)(j * 16 + ln) * 4096);
          acc[j] = __builtin_amdgcn_mfma_f32_16x16x32_f16(afr, bfr, acc[j], 0, 0, 0);
        }
      }
    }
#pragma unroll
    for (int j = 0; j < 20; j++) {
      const int f = j * 16 + ln;
      if (f < NC) {
#pragma unroll
        for (int r = 0; r < 4; r++)
          Qb[(size_t)(j0 + wv * 16 + q * 4 + r) * NC + f] = acc[j][r];
      }
    }
  }
}

// ---------------- tail ---------------------------------------------------------
__global__ void reduce_uv(const float* __restrict__ X, const float* __restrict__ Yp,
                          float* __restrict__ inp, int off)
{
  const int j = threadIdx.x;
  if (j >= NC) return;
  const int r0 = blockIdx.x * 128;
  float s = 0.f;
  for (int r = r0; r < r0 + 128; r++)
    s += fmaxf(X[(size_t)r * NC + j], Yp[(size_t)r * NC + j]);
  atomicAdd(&inp[off + j], s);
}

__global__ void fc1_k(const float* __restrict__ w1, const float* __restrict__ b1,
                      const float* __restrict__ inp, float* __restrict__ x)
{
  const int r = blockIdx.x * 256 + threadIdx.x;
  if (r >= 2000) return;
  float s = b1[r];
  const float* wr = w1 + (size_t)r * 600;
  for (int k = 0; k < 600; k++) s += wr[k] * inp[k];
  x[r] = fmaxf(s, 0.f);
}

__global__ void fc2_k(const float* __restrict__ x, const float* __restrict__ w2,
                      const float* __restrict__ b2, float* __restrict__ outp)
{
  const int tid = threadIdx.x;
  float s = 0.f;
  for (int i = tid; i < 2000; i += 256) s += x[i] * w2[i];
#pragma unroll
  for (int off = 32; off > 0; off >>= 1) s += __shfl_down(s, off);
  __shared__ float red[4];
  if ((tid & 63) == 0) red[tid >> 6] = s;
  __syncthreads();
  if (tid == 0) outp[0] = red[0] + red[1] + red[2] + red[3] + b2[0];
}

// ---------------- launch --------------------------------------------------------
extern "C" void kernel_launch(void* const* d_in, const int* in_sizes, int n_in,
                              void* d_out, int out_size, void* d_ws, size_t ws_size,
                              hipStream_t stream)
{
  const float* in_solv  = (const float*)d_in[0];
  const float* in_solu  = (const float*)d_in[1];
  const float* solv_Wih = (const float*)d_in[2];
  const float* solv_Whh = (const float*)d_in[3];
  const float* solv_bih = (const float*)d_in[4];
  const float* solv_bhh = (const float*)d_in[5];
  const float* solu_Wih = (const float*)d_in[6];
  const float* solu_Whh = (const float*)d_in[7];
  const float* solu_bih = (const float*)d_in[8];
  const float* solu_bhh = (const float*)d_in[9];
  const float* fc1_w = (const float*)d_in[10];
  const float* fc1_b = (const float*)d_in[11];
  const float* fc2_w = (const float*)d_in[12];
  const float* fc2_b = (const float*)d_in[13];
  float* outp = (float*)d_out;
  float* ws = (float*)d_ws;

  // ---- workspace layout (float offsets); peak 16,067,200 fl < prior 17.2M ----
  // off_P:  Wihh (819,200 fl) early -> Pb fp32 late (Wihh dead after xg_mfma l1)
  // off_xg: xg (9,830,400 fl) -> AH fp16 (8,388,608 fl) + HhT/GhT (655,360 fl)
  // off_L0: Avh/Auh fp16 -> Hh/Gh fp16 (pads inherited from conv_x zeros)
  // off_HG: L0vh/L0uh fp16 (pads pre-zeroed) -> Hb/Gb fp32 (after xg_mfma l1)
  constexpr size_t off_P   = 0;
  constexpr size_t off_Q   = 1228800;
  constexpr size_t off_inp = 2457600;   // 640
  constexpr size_t off_x   = 2458240;   // 2048
  constexpr size_t off_il  = 2460288;   // 4096
  constexpr size_t off_xg  = 2468480;
  constexpr size_t off_L0  = off_xg + (size_t)4 * 2457600;   // 12,298,880
  constexpr size_t off_HG  = off_L0 + 1310720;               // 13,609,600

  float*  xg   = ws + off_xg;
  float*  Hb   = ws + off_HG;
  float*  Gb   = Hb + 1228800;
  float*  Pb   = ws + off_P;
  float*  Qb   = ws + off_Q;
  float*  inp  = ws + off_inp;
  float*  xf   = ws + off_x;
  float*  il   = ws + off_il;
  __half* Wihh = (__half*)(ws + off_P);
  __half* Avh  = (__half*)(ws + off_L0);
  __half* Auh  = Avh + 4096 * 320;
  __half* L0vh = (__half*)(ws + off_HG);
  __half* L0uh = L0vh + 4096 * 320;
  __half* Hh   = (__half*)(ws + off_L0);   // reuses Avh/Auh space (dead)
  __half* Gh   = Hh + 4096 * 320;
  __half* AH   = (__half*)(ws + off_xg);   // after scans (xg dead)
  __half* HhT  = AH + (size_t)4096 * 4096;
  __half* GhT  = HhT + 320 * 4096;

  // ---- prep: zero L0vh/L0uh pads, convert weights + inputs to fp16 ----
  zero_f<<<5120, 256, 0, stream>>>(ws + off_HG, 1310720);
  conv_w<<<(8 * 640 * 320 + 255) / 256, 256, 0, stream>>>(solv_Wih, solu_Wih, Wihh);
  conv_x<<<5120, 256, 0, stream>>>(in_solv, Avh, 4096);
  conv_x<<<5120, 256, 0, stream>>>(in_solu, Auh, 4096);

  // ---- layer 0 (scan writes fp16 L0vh/L0uh directly; no fp32 out) ----
  xg_mfma<<<dim3(64, 4), 256, 0, stream>>>(Avh, Auh, Wihh,
      solv_bih, solv_bhh, solu_bih, solu_bhh, xg, 0);
  lstm_scan<0><<<4, 512, 0, stream>>>(solv_Whh, solu_Whh, xg,
      nullptr, nullptr, L0vh, L0uh, 0);

  // ---- layer 1 (scan writes fp32 Hb/Gb + fp16 Hh/Gh) ----
  xg_mfma<<<dim3(64, 4), 256, 0, stream>>>(L0vh, L0uh, Wihh + (size_t)4 * 640 * 320,
      solv_bih, solv_bhh, solu_bih, solu_bhh, xg, 1);
  lstm_scan<1><<<4, 512, 0, stream>>>(solv_Whh, solu_Whh, xg,
      Hb, Gb, Hh, Gh, 1);

  // ---- attention: S once (fp16), rowsum, scale, P/Q combined ----
  conv_t<<<5120, 256, 0, stream>>>(Hb, HhT);
  conv_t<<<5120, 256, 0, stream>>>(Gb, GhT);
  s_gemm<<<dim3(64, 4), 256, 0, stream>>>(Hh, Gh, AH);
  rowsum_k<<<4096, 256, 0, stream>>>(AH, il);
  scale_k<<<8192, 256, 0, stream>>>(AH, il);
  pq_mfma<<<128, 256, 0, stream>>>(AH, GhT, HhT, Pb, Qb);

  // ---- tail ----
  zero_f<<<3, 256, 0, stream>>>(inp, 640);
  reduce_uv<<<32, 320, 0, stream>>>(Hb, Pb, inp, 0);
  reduce_uv<<<32, 320, 0, stream>>>(Gb, Qb, inp, 300);
  fc1_k<<<8, 256, 0, stream>>>(fc1_w, fc1_b, inp, xf);
  fc2_k<<<1, 256, 0, stream>>>(xf, fc2_w, fc2_b, outp);
}